// Round 6
// baseline (433.406 us; speedup 1.0000x reference)
//
#include <hip/hip_runtime.h>

#define NN 100000
#define NE 1600000
#define FIN 256
#define FH 64
#define FC 16

#define SCAN_CHUNK 1024
#define NB_SCAN ((NN + SCAN_CHUNK - 1) / SCAN_CHUNK)   // 98
#define NSWEEP 4
#define SWEEP_W ((NN + NSWEEP - 1) / NSWEEP)           // 25000
#define NSLICE 8

typedef int v4i __attribute__((ext_vector_type(4)));

// ---- edge-index dtype robustness: int64 vs int32 detection -----------------
__global__ void detect_k(const int* __restrict__ ei, int* __restrict__ flag) {
    if (threadIdx.x == 0 && blockIdx.x == 0) {
        int z = (ei[1] == 0) & (ei[3] == 0) & (ei[5] == 0) & (ei[7] == 0);
        *flag = z;   // 1 => int64 layout, 0 => int32 layout
    }
}

__device__ __forceinline__ int eidx(const int* __restrict__ ei, int f, int pos) {
    return f ? ei[2 * pos] : ei[pos];
}

// ---- count, XCD-sliced: slice = blockIdx & 7 ~ XCD id (round-robin) --------
// deg_s[slice][d] atomics stay in one XCD's L2 -> no cross-die line bouncing.
__global__ __launch_bounds__(256) void count_k(const int* __restrict__ ei,
                                               const int* __restrict__ flag,
                                               int* __restrict__ deg_s,
                                               v4i* __restrict__ packed) {
    int e = blockIdx.x * 256 + threadIdx.x;
    if (e >= NE) return;
    int f = *flag;
    int slice = blockIdx.x & (NSLICE - 1);
    int s = eidx(ei, f, e);
    int d = eidx(ei, f, NE + e);
    int r = atomicAdd(&deg_s[slice * NN + d], 1);
    v4i p; p.x = s; p.y = d; p.z = r; p.w = slice;
    packed[e] = p;
}

// ---- combine slices: deg_s -> exclusive slice bases (in-place), deg, dinv --
__global__ __launch_bounds__(256) void combine_k(int* __restrict__ deg_s,
                                                 int* __restrict__ deg,
                                                 float* __restrict__ dinv) {
    int n = blockIdx.x * 256 + threadIdx.x;
    if (n >= NN) return;
    int c[NSLICE]; int tot = 0;
    #pragma unroll
    for (int s = 0; s < NSLICE; s++) c[s] = deg_s[s * NN + n];
    #pragma unroll
    for (int s = 0; s < NSLICE; s++) { int v = c[s]; deg_s[s * NN + n] = tot; tot += v; }
    deg[n] = tot;
    dinv[n] = rsqrtf((float)(tot + 1));   // +1 self-loop
}

// ---- multi-block exclusive scan: pass 1, per-block sums --------------------
__global__ __launch_bounds__(256) void scan_sum_k(const int* __restrict__ deg,
                                                  int* __restrict__ partial) {
    __shared__ int red[256];
    int b = blockIdx.x, t = threadIdx.x;
    int base = b * SCAN_CHUNK + t * 4;
    int s = 0;
    #pragma unroll
    for (int i = 0; i < 4; i++) { int idx = base + i; if (idx < NN) s += deg[idx]; }
    red[t] = s;
    __syncthreads();
    for (int off = 128; off > 0; off >>= 1) {
        if (t < off) red[t] += red[t + off];
        __syncthreads();
    }
    if (t == 0) partial[b] = red[0];
}

// ---- pass 2: single small block exclusive-scans the partials ---------------
__global__ __launch_bounds__(128) void scan_part_k(int* __restrict__ partial) {
    __shared__ int s[128];
    int t = threadIdx.x;
    int v = (t < NB_SCAN) ? partial[t] : 0;
    s[t] = v; __syncthreads();
    for (int off = 1; off < 128; off <<= 1) {
        int u = (t >= off) ? s[t - off] : 0;
        __syncthreads();
        s[t] += u;
        __syncthreads();
    }
    if (t < NB_SCAN) partial[t] = s[t] - v;   // exclusive
}

// ---- pass 3: per-block local scan + offset -> row_start --------------------
__global__ __launch_bounds__(256) void scan_out_k(const int* __restrict__ deg,
                                                  const int* __restrict__ partial,
                                                  int* __restrict__ row_start) {
    __shared__ int s[256];
    int b = blockIdx.x, t = threadIdx.x;
    int base = b * SCAN_CHUNK + t * 4;
    int v[4]; int sum = 0;
    #pragma unroll
    for (int i = 0; i < 4; i++) {
        int idx = base + i;
        v[i] = (idx < NN) ? deg[idx] : 0;
        sum += v[i];
    }
    s[t] = sum; __syncthreads();
    for (int off = 1; off < 256; off <<= 1) {
        int u = (t >= off) ? s[t - off] : 0;
        __syncthreads();
        s[t] += u;
        __syncthreads();
    }
    int run = partial[b] + s[t] - sum;
    #pragma unroll
    for (int i = 0; i < 4; i++) {
        int idx = base + i;
        if (idx < NN) {
            row_start[idx] = run;
            run += v[i];
            if (idx == NN - 1) row_start[NN] = run;   // == NE
        }
    }
}

// ---- CSR fill, dst-range sweep: pure store, no atomic ----------------------
__global__ __launch_bounds__(256) void fill_k(const v4i* __restrict__ packed,
                                              const int* __restrict__ row_start,
                                              const int* __restrict__ sbase,
                                              int* __restrict__ csr,
                                              int lo, int hi) {
    int e = blockIdx.x * 256 + threadIdx.x;
    if (e >= NE) return;
    v4i p = __builtin_nontemporal_load(&packed[e]);   // (src, dst, local_rank, slice)
    if (p.y < lo || p.y >= hi) return;
    csr[row_start[p.y] + sbase[p.w * NN + p.y] + p.z] = p.x;
}

// ---- GEMM1: h1[NN][64] = x[NN][256] @ W1[256][64] --------------------------
__global__ __launch_bounds__(256) void gemm1_k(const float* __restrict__ x,
                                               const float* __restrict__ W,
                                               float* __restrict__ h) {
    __shared__ float As[64][68];
    __shared__ float Bs[64][64];
    const int t = threadIdx.x;
    const int r0 = blockIdx.x * 64;
    const int tx4 = (t & 15) * 4;
    const int ty4 = (t >> 4) * 4;
    const int lrow = t >> 4;
    const int lkf = (t & 15) * 4;

    float acc[4][4] = {};

    for (int k0 = 0; k0 < FIN; k0 += 64) {
        #pragma unroll
        for (int i = 0; i < 4; i++) {
            int row = lrow + 16 * i;
            int gr = r0 + row;
            float4 v = make_float4(0.f, 0.f, 0.f, 0.f);
            if (gr < NN) v = *(const float4*)&x[gr * FIN + k0 + lkf];
            As[lkf + 0][row] = v.x;
            As[lkf + 1][row] = v.y;
            As[lkf + 2][row] = v.z;
            As[lkf + 3][row] = v.w;
            float4 w = *(const float4*)&W[(k0 + row) * FH + lkf];
            *(float4*)&Bs[row][lkf] = w;
        }
        __syncthreads();
        #pragma unroll 8
        for (int kk = 0; kk < 64; kk++) {
            float4 a = *(const float4*)&As[kk][ty4];
            float4 b = *(const float4*)&Bs[kk][tx4];
            float av[4] = {a.x, a.y, a.z, a.w};
            float bv[4] = {b.x, b.y, b.z, b.w};
            #pragma unroll
            for (int i2 = 0; i2 < 4; i2++)
                #pragma unroll
                for (int j2 = 0; j2 < 4; j2++)
                    acc[i2][j2] = fmaf(av[i2], bv[j2], acc[i2][j2]);
        }
        __syncthreads();
    }
    #pragma unroll
    for (int i2 = 0; i2 < 4; i2++) {
        int r = r0 + ty4 + i2;
        if (r < NN)
            *(float4*)&h[r * FH + tx4] =
                make_float4(acc[i2][0], acc[i2][1], acc[i2][2], acc[i2][3]);
    }
}

// ---- aggregate layer1: one wave per node, lane = feature, 4-deep MLP -------
__global__ __launch_bounds__(256) void agg1_k(const int* __restrict__ csr,
                                              const int* __restrict__ row_start,
                                              const float* __restrict__ h1,
                                              const float* __restrict__ dinv,
                                              const float* __restrict__ b1,
                                              float* __restrict__ agg) {
    int n = blockIdx.x * 4 + (threadIdx.x >> 6);
    int lane = threadIdx.x & 63;
    if (n >= NN) return;
    int s0 = row_start[n], s1 = row_start[n + 1];
    float acc = 0.f, a0 = 0.f, a1 = 0.f, a2 = 0.f, a3 = 0.f;
    for (int j0 = s0; j0 < s1; j0 += 64) {
        int idx = j0 + lane;
        int sl = 0; float wl = 0.f;
        if (idx < s1) { sl = csr[idx]; wl = dinv[sl]; }
        int cnt = s1 - j0; if (cnt > 64) cnt = 64;
        int j = 0;
        for (; j + 4 <= cnt; j += 4) {
            int   sA = __shfl(sl, j + 0, 64), sB = __shfl(sl, j + 1, 64);
            int   sC = __shfl(sl, j + 2, 64), sD = __shfl(sl, j + 3, 64);
            float wA = __shfl(wl, j + 0, 64), wB = __shfl(wl, j + 1, 64);
            float wC = __shfl(wl, j + 2, 64), wD = __shfl(wl, j + 3, 64);
            float hA = h1[sA * FH + lane];
            float hB = h1[sB * FH + lane];
            float hC = h1[sC * FH + lane];
            float hD = h1[sD * FH + lane];
            a0 = fmaf(hA, wA, a0); a1 = fmaf(hB, wB, a1);
            a2 = fmaf(hC, wC, a2); a3 = fmaf(hD, wD, a3);
        }
        for (; j < cnt; j++) {
            int   s = __shfl(sl, j, 64);
            float w = __shfl(wl, j, 64);
            acc = fmaf(h1[s * FH + lane], w, acc);
        }
    }
    acc += (a0 + a1) + (a2 + a3);
    float dn = dinv[n];
    acc = fmaf(h1[n * FH + lane], dn, acc);
    agg[n * FH + lane] = fmaf(acc, dn, b1[lane]);
}

// ---- GEMM2 + relu: h2[NN][16] = relu(agg1) @ W2[64][16] -------------------
__global__ __launch_bounds__(192) void gemm2_k(const float* __restrict__ agg,
                                               const float* __restrict__ W2,
                                               float* __restrict__ h2) {
    __shared__ float a_lds[192 * 65];
    const int t = threadIdx.x;
    const int r0 = blockIdx.x * 192;
    #pragma unroll
    for (int i = 0; i < 16; i++) {
        int fidx = t + 192 * i;
        int row = fidx >> 4, kf = (fidx & 15) * 4;
        int gr = r0 + row;
        float4 v = make_float4(0.f, 0.f, 0.f, 0.f);
        if (gr < NN) v = *(const float4*)&agg[gr * FH + kf];
        v.x = fmaxf(v.x, 0.f); v.y = fmaxf(v.y, 0.f);
        v.z = fmaxf(v.z, 0.f); v.w = fmaxf(v.w, 0.f);
        a_lds[row * 65 + kf + 0] = v.x;
        a_lds[row * 65 + kf + 1] = v.y;
        a_lds[row * 65 + kf + 2] = v.z;
        a_lds[row * 65 + kf + 3] = v.w;
    }
    __syncthreads();
    float acc[FC] = {};
    #pragma unroll 4
    for (int k = 0; k < FH; k++) {
        float a = a_lds[t * 65 + k];
        #pragma unroll
        for (int c = 0; c < FC; c++)
            acc[c] = fmaf(a, W2[k * FC + c], acc[c]);
    }
    int r = r0 + t;
    if (r < NN) {
        #pragma unroll
        for (int q = 0; q < 4; q++)
            *(float4*)&h2[r * FC + 4 * q] =
                make_float4(acc[4*q], acc[4*q+1], acc[4*q+2], acc[4*q+3]);
    }
}

// ---- aggregate layer2: 16-lane subgroup per node, 4-deep MLP ---------------
__global__ __launch_bounds__(256) void agg2_k(const int* __restrict__ csr,
                                              const int* __restrict__ row_start,
                                              const float* __restrict__ h2,
                                              const float* __restrict__ dinv,
                                              const float* __restrict__ b2,
                                              float* __restrict__ out) {
    int n = blockIdx.x * 16 + (threadIdx.x >> 4);
    int l16 = threadIdx.x & 15;
    int base = threadIdx.x & 48;
    if (n >= NN) return;
    int s0 = row_start[n], s1 = row_start[n + 1];
    float acc = 0.f, a0 = 0.f, a1 = 0.f, a2 = 0.f, a3 = 0.f;
    for (int j0 = s0; j0 < s1; j0 += 16) {
        int idx = j0 + l16;
        int sl = 0; float wl = 0.f;
        if (idx < s1) { sl = csr[idx]; wl = dinv[sl]; }
        int cnt = s1 - j0; if (cnt > 16) cnt = 16;
        int j = 0;
        for (; j + 4 <= cnt; j += 4) {
            int   sA = __shfl(sl, base + j + 0, 64), sB = __shfl(sl, base + j + 1, 64);
            int   sC = __shfl(sl, base + j + 2, 64), sD = __shfl(sl, base + j + 3, 64);
            float wA = __shfl(wl, base + j + 0, 64), wB = __shfl(wl, base + j + 1, 64);
            float wC = __shfl(wl, base + j + 2, 64), wD = __shfl(wl, base + j + 3, 64);
            float hA = h2[sA * FC + l16];
            float hB = h2[sB * FC + l16];
            float hC = h2[sC * FC + l16];
            float hD = h2[sD * FC + l16];
            a0 = fmaf(hA, wA, a0); a1 = fmaf(hB, wB, a1);
            a2 = fmaf(hC, wC, a2); a3 = fmaf(hD, wD, a3);
        }
        for (; j < cnt; j++) {
            int   s = __shfl(sl, base + j, 64);
            float w = __shfl(wl, base + j, 64);
            acc = fmaf(h2[s * FC + l16], w, acc);
        }
    }
    acc += (a0 + a1) + (a2 + a3);
    float dn = dinv[n];
    acc = fmaf(h2[n * FC + l16], dn, acc);
    out[n * FC + l16] = fmaf(acc, dn, b2[l16]);
}

extern "C" void kernel_launch(void* const* d_in, const int* in_sizes, int n_in,
                              void* d_out, int out_size, void* d_ws, size_t ws_size,
                              hipStream_t stream) {
    const float* x  = (const float*)d_in[0];
    const int*   ei = (const int*)d_in[1];
    const float* W1 = (const float*)d_in[2];
    const float* b1 = (const float*)d_in[3];
    const float* W2 = (const float*)d_in[4];
    const float* b2 = (const float*)d_in[5];
    float* out = (float*)d_out;

    char* ws = (char*)d_ws;
    int*   deg       = (int*)(ws + 0);                       // 400 KB
    int*   row_start = (int*)(ws + 512 * 1024);              // 400 KB + 4
    float* dinv      = (float*)(ws + 1024 * 1024);           // 400 KB
    int*   flag      = (int*)(ws + 1536 * 1024);             // 4 B
    int*   partial   = (int*)(ws + 1540 * 1024);             // 392 B
    int*   csr       = (int*)(ws + 2ull * 1024 * 1024);      // 6.4 MB
    // packed (25.6 MB) aliases h1: fill_k finishes before gemm1_k writes h1.
    v4i*   packed    = (v4i*)(ws + 9ull * 1024 * 1024);      // 25.6 MB
    float* h1        = (float*)(ws + 9ull * 1024 * 1024);    // 25.6 MB
    float* agg1      = (float*)(ws + 35ull * 1024 * 1024);   // 25.6 MB
    // deg_s/sbase (3.2 MB) alias agg1's head: last read in fill_k, and agg1
    // is first written by agg1_k (strictly after) -> disjoint lifetimes.
    int*   deg_s     = (int*)(ws + 35ull * 1024 * 1024);     // 8 x 400 KB
    float* h2        = h1;   // alias: h1 dead after agg1_k

    detect_k<<<1, 64, 0, stream>>>(ei, flag);
    (void)hipMemsetAsync(deg_s, 0, NSLICE * NN * sizeof(int), stream);
    count_k<<<(NE + 255) / 256, 256, 0, stream>>>(ei, flag, deg_s, packed);
    combine_k<<<(NN + 255) / 256, 256, 0, stream>>>(deg_s, deg, dinv);
    scan_sum_k<<<NB_SCAN, 256, 0, stream>>>(deg, partial);
    scan_part_k<<<1, 128, 0, stream>>>(partial);
    scan_out_k<<<NB_SCAN, 256, 0, stream>>>(deg, partial, row_start);
    for (int sw = 0; sw < NSWEEP; sw++)
        fill_k<<<(NE + 255) / 256, 256, 0, stream>>>(packed, row_start, deg_s, csr,
                                                     sw * SWEEP_W, (sw + 1) * SWEEP_W);

    gemm1_k<<<(NN + 63) / 64, 256, 0, stream>>>(x, W1, h1);   // overwrites packed
    agg1_k<<<(NN + 3) / 4, 256, 0, stream>>>(csr, row_start, h1, dinv, b1, agg1);

    gemm2_k<<<(NN + 191) / 192, 192, 0, stream>>>(agg1, W2, h2);
    agg2_k<<<(NN + 15) / 16, 256, 0, stream>>>(csr, row_start, h2, dinv, b2, out);
}

// Round 7
// 397.953 us; speedup vs baseline: 1.0891x; 1.0891x over previous
//
#include <hip/hip_runtime.h>

#define NN 100000
#define NE 1600000
#define FIN 256
#define FH 64
#define FC 16

#define SCAN_CHUNK 1024
#define NB_SCAN ((NN + SCAN_CHUNK - 1) / SCAN_CHUNK)   // 98
#define NSWEEP 2
#define SWEEP_W ((NN + NSWEEP - 1) / NSWEEP)           // 50000
#define NB_COUNT ((NE + 255) / 256)                    // 6250
#define NB_GEMM1 ((NN + 63) / 64)                      // 1563

typedef int v2i __attribute__((ext_vector_type(2)));

// ---- edge-index dtype robustness: int64 vs int32 detection -----------------
__global__ void detect_k(const int* __restrict__ ei, int* __restrict__ flag) {
    if (threadIdx.x == 0 && blockIdx.x == 0) {
        int z = (ei[1] == 0) & (ei[3] == 0) & (ei[5] == 0) & (ei[7] == 0);
        *flag = z;   // 1 => int64 layout, 0 => int32 layout
    }
}

__device__ __forceinline__ int eidx(const int* __restrict__ ei, int f, int pos) {
    return f ? ei[2 * pos] : ei[pos];
}

// ---- FUSED: count+rank+pack (blocks < NB_COUNT) || GEMM1 (rest) ------------
// Count blocks are memory-side-atomic-bound (VALU ~1%); GEMM blocks fill the
// idle VALU/LDS on the same CUs -> overlap hides gemm1 under the atomic floor.
// packed[e] = (src, dst | rank<<17)  [dst<2^17, rank<2^12 on this input]
__global__ __launch_bounds__(256) void fused_k(const int* __restrict__ ei,
                                               const int* __restrict__ flag,
                                               int* __restrict__ deg,
                                               v2i* __restrict__ packed,
                                               const float* __restrict__ x,
                                               const float* __restrict__ W,
                                               float* __restrict__ h) {
    if (blockIdx.x < NB_COUNT) {
        int e = blockIdx.x * 256 + threadIdx.x;
        if (e >= NE) return;
        int f = *flag;
        int s = eidx(ei, f, e);
        int d = eidx(ei, f, NE + e);
        int r = atomicAdd(&deg[d], 1);
        v2i p; p.x = s; p.y = d | (r << 17);
        packed[e] = p;
        return;
    }
    // ---- GEMM1: h[NN][64] = x[NN][256] @ W[256][64], 64x64 tile ----
    __shared__ float As[64][68];
    __shared__ float Bs[64][64];
    const int t = threadIdx.x;
    const int r0 = (blockIdx.x - NB_COUNT) * 64;
    const int tx4 = (t & 15) * 4;
    const int ty4 = (t >> 4) * 4;
    const int lrow = t >> 4;
    const int lkf = (t & 15) * 4;

    float acc[4][4] = {};

    for (int k0 = 0; k0 < FIN; k0 += 64) {
        #pragma unroll
        for (int i = 0; i < 4; i++) {
            int row = lrow + 16 * i;
            int gr = r0 + row;
            float4 v = make_float4(0.f, 0.f, 0.f, 0.f);
            if (gr < NN) v = *(const float4*)&x[gr * FIN + k0 + lkf];
            As[lkf + 0][row] = v.x;
            As[lkf + 1][row] = v.y;
            As[lkf + 2][row] = v.z;
            As[lkf + 3][row] = v.w;
            float4 w = *(const float4*)&W[(k0 + row) * FH + lkf];
            *(float4*)&Bs[row][lkf] = w;
        }
        __syncthreads();
        #pragma unroll 8
        for (int kk = 0; kk < 64; kk++) {
            float4 a = *(const float4*)&As[kk][ty4];
            float4 b = *(const float4*)&Bs[kk][tx4];
            float av[4] = {a.x, a.y, a.z, a.w};
            float bv[4] = {b.x, b.y, b.z, b.w};
            #pragma unroll
            for (int i2 = 0; i2 < 4; i2++)
                #pragma unroll
                for (int j2 = 0; j2 < 4; j2++)
                    acc[i2][j2] = fmaf(av[i2], bv[j2], acc[i2][j2]);
        }
        __syncthreads();
    }
    #pragma unroll
    for (int i2 = 0; i2 < 4; i2++) {
        int r = r0 + ty4 + i2;
        if (r < NN)
            *(float4*)&h[r * FH + tx4] =
                make_float4(acc[i2][0], acc[i2][1], acc[i2][2], acc[i2][3]);
    }
}

__global__ void dinv_k(const int* __restrict__ deg, float* __restrict__ dinv) {
    int i = blockIdx.x * 256 + threadIdx.x;
    if (i < NN) dinv[i] = rsqrtf((float)(deg[i] + 1));  // +1 self-loop
}

// ---- multi-block exclusive scan: pass 1, per-block sums --------------------
__global__ __launch_bounds__(256) void scan_sum_k(const int* __restrict__ deg,
                                                  int* __restrict__ partial) {
    __shared__ int red[256];
    int b = blockIdx.x, t = threadIdx.x;
    int base = b * SCAN_CHUNK + t * 4;
    int s = 0;
    #pragma unroll
    for (int i = 0; i < 4; i++) { int idx = base + i; if (idx < NN) s += deg[idx]; }
    red[t] = s;
    __syncthreads();
    for (int off = 128; off > 0; off >>= 1) {
        if (t < off) red[t] += red[t + off];
        __syncthreads();
    }
    if (t == 0) partial[b] = red[0];
}

// ---- pass 2: single small block exclusive-scans the partials ---------------
__global__ __launch_bounds__(128) void scan_part_k(int* __restrict__ partial) {
    __shared__ int s[128];
    int t = threadIdx.x;
    int v = (t < NB_SCAN) ? partial[t] : 0;
    s[t] = v; __syncthreads();
    for (int off = 1; off < 128; off <<= 1) {
        int u = (t >= off) ? s[t - off] : 0;
        __syncthreads();
        s[t] += u;
        __syncthreads();
    }
    if (t < NB_SCAN) partial[t] = s[t] - v;   // exclusive
}

// ---- pass 3: per-block local scan + offset -> row_start --------------------
__global__ __launch_bounds__(256) void scan_out_k(const int* __restrict__ deg,
                                                  const int* __restrict__ partial,
                                                  int* __restrict__ row_start) {
    __shared__ int s[256];
    int b = blockIdx.x, t = threadIdx.x;
    int base = b * SCAN_CHUNK + t * 4;
    int v[4]; int sum = 0;
    #pragma unroll
    for (int i = 0; i < 4; i++) {
        int idx = base + i;
        v[i] = (idx < NN) ? deg[idx] : 0;
        sum += v[i];
    }
    s[t] = sum; __syncthreads();
    for (int off = 1; off < 256; off <<= 1) {
        int u = (t >= off) ? s[t - off] : 0;
        __syncthreads();
        s[t] += u;
        __syncthreads();
    }
    int run = partial[b] + s[t] - sum;
    #pragma unroll
    for (int i = 0; i < 4; i++) {
        int idx = base + i;
        if (idx < NN) {
            row_start[idx] = run;
            run += v[i];
            if (idx == NN - 1) row_start[NN] = run;   // == NE
        }
    }
}

// ---- CSR fill, dst-range sweep: pure store, no atomic ----------------------
__global__ __launch_bounds__(256) void fill_k(const v2i* __restrict__ packed,
                                              const int* __restrict__ row_start,
                                              int* __restrict__ csr,
                                              int lo, int hi) {
    int e = blockIdx.x * 256 + threadIdx.x;
    if (e >= NE) return;
    v2i p = __builtin_nontemporal_load(&packed[e]);   // (src, dst|rank<<17)
    int d = p.y & 0x1FFFF;
    if (d < lo || d >= hi) return;
    int r = ((unsigned)p.y) >> 17;
    csr[row_start[d] + r] = p.x;
}

// ---- aggregate layer1: one wave per node, lane = feature, 4-deep MLP -------
__global__ __launch_bounds__(256) void agg1_k(const int* __restrict__ csr,
                                              const int* __restrict__ row_start,
                                              const float* __restrict__ h1,
                                              const float* __restrict__ dinv,
                                              const float* __restrict__ b1,
                                              float* __restrict__ agg) {
    int n = blockIdx.x * 4 + (threadIdx.x >> 6);
    int lane = threadIdx.x & 63;
    if (n >= NN) return;
    int s0 = row_start[n], s1 = row_start[n + 1];
    float acc = 0.f, a0 = 0.f, a1 = 0.f, a2 = 0.f, a3 = 0.f;
    for (int j0 = s0; j0 < s1; j0 += 64) {
        int idx = j0 + lane;
        int sl = 0; float wl = 0.f;
        if (idx < s1) { sl = csr[idx]; wl = dinv[sl]; }
        int cnt = s1 - j0; if (cnt > 64) cnt = 64;
        int j = 0;
        for (; j + 4 <= cnt; j += 4) {
            int   sA = __shfl(sl, j + 0, 64), sB = __shfl(sl, j + 1, 64);
            int   sC = __shfl(sl, j + 2, 64), sD = __shfl(sl, j + 3, 64);
            float wA = __shfl(wl, j + 0, 64), wB = __shfl(wl, j + 1, 64);
            float wC = __shfl(wl, j + 2, 64), wD = __shfl(wl, j + 3, 64);
            float hA = h1[sA * FH + lane];
            float hB = h1[sB * FH + lane];
            float hC = h1[sC * FH + lane];
            float hD = h1[sD * FH + lane];
            a0 = fmaf(hA, wA, a0); a1 = fmaf(hB, wB, a1);
            a2 = fmaf(hC, wC, a2); a3 = fmaf(hD, wD, a3);
        }
        for (; j < cnt; j++) {
            int   s = __shfl(sl, j, 64);
            float w = __shfl(wl, j, 64);
            acc = fmaf(h1[s * FH + lane], w, acc);
        }
    }
    acc += (a0 + a1) + (a2 + a3);
    float dn = dinv[n];
    acc = fmaf(h1[n * FH + lane], dn, acc);
    agg[n * FH + lane] = fmaf(acc, dn, b1[lane]);
}

// ---- GEMM2 + relu: h2[NN][16] = relu(agg1) @ W2[64][16] -------------------
__global__ __launch_bounds__(192) void gemm2_k(const float* __restrict__ agg,
                                               const float* __restrict__ W2,
                                               float* __restrict__ h2) {
    __shared__ float a_lds[192 * 65];
    const int t = threadIdx.x;
    const int r0 = blockIdx.x * 192;
    #pragma unroll
    for (int i = 0; i < 16; i++) {
        int fidx = t + 192 * i;
        int row = fidx >> 4, kf = (fidx & 15) * 4;
        int gr = r0 + row;
        float4 v = make_float4(0.f, 0.f, 0.f, 0.f);
        if (gr < NN) v = *(const float4*)&agg[gr * FH + kf];
        v.x = fmaxf(v.x, 0.f); v.y = fmaxf(v.y, 0.f);
        v.z = fmaxf(v.z, 0.f); v.w = fmaxf(v.w, 0.f);
        a_lds[row * 65 + kf + 0] = v.x;
        a_lds[row * 65 + kf + 1] = v.y;
        a_lds[row * 65 + kf + 2] = v.z;
        a_lds[row * 65 + kf + 3] = v.w;
    }
    __syncthreads();
    float acc[FC] = {};
    #pragma unroll 4
    for (int k = 0; k < FH; k++) {
        float a = a_lds[t * 65 + k];
        #pragma unroll
        for (int c = 0; c < FC; c++)
            acc[c] = fmaf(a, W2[k * FC + c], acc[c]);
    }
    int r = r0 + t;
    if (r < NN) {
        #pragma unroll
        for (int q = 0; q < 4; q++)
            *(float4*)&h2[r * FC + 4 * q] =
                make_float4(acc[4*q], acc[4*q+1], acc[4*q+2], acc[4*q+3]);
    }
}

// ---- aggregate layer2: 16-lane subgroup per node, 4-deep MLP ---------------
__global__ __launch_bounds__(256) void agg2_k(const int* __restrict__ csr,
                                              const int* __restrict__ row_start,
                                              const float* __restrict__ h2,
                                              const float* __restrict__ dinv,
                                              const float* __restrict__ b2,
                                              float* __restrict__ out) {
    int n = blockIdx.x * 16 + (threadIdx.x >> 4);
    int l16 = threadIdx.x & 15;
    int base = threadIdx.x & 48;
    if (n >= NN) return;
    int s0 = row_start[n], s1 = row_start[n + 1];
    float acc = 0.f, a0 = 0.f, a1 = 0.f, a2 = 0.f, a3 = 0.f;
    for (int j0 = s0; j0 < s1; j0 += 16) {
        int idx = j0 + l16;
        int sl = 0; float wl = 0.f;
        if (idx < s1) { sl = csr[idx]; wl = dinv[sl]; }
        int cnt = s1 - j0; if (cnt > 16) cnt = 16;
        int j = 0;
        for (; j + 4 <= cnt; j += 4) {
            int   sA = __shfl(sl, base + j + 0, 64), sB = __shfl(sl, base + j + 1, 64);
            int   sC = __shfl(sl, base + j + 2, 64), sD = __shfl(sl, base + j + 3, 64);
            float wA = __shfl(wl, base + j + 0, 64), wB = __shfl(wl, base + j + 1, 64);
            float wC = __shfl(wl, base + j + 2, 64), wD = __shfl(wl, base + j + 3, 64);
            float hA = h2[sA * FC + l16];
            float hB = h2[sB * FC + l16];
            float hC = h2[sC * FC + l16];
            float hD = h2[sD * FC + l16];
            a0 = fmaf(hA, wA, a0); a1 = fmaf(hB, wB, a1);
            a2 = fmaf(hC, wC, a2); a3 = fmaf(hD, wD, a3);
        }
        for (; j < cnt; j++) {
            int   s = __shfl(sl, base + j, 64);
            float w = __shfl(wl, base + j, 64);
            acc = fmaf(h2[s * FC + l16], w, acc);
        }
    }
    acc += (a0 + a1) + (a2 + a3);
    float dn = dinv[n];
    acc = fmaf(h2[n * FC + l16], dn, acc);
    out[n * FC + l16] = fmaf(acc, dn, b2[l16]);
}

extern "C" void kernel_launch(void* const* d_in, const int* in_sizes, int n_in,
                              void* d_out, int out_size, void* d_ws, size_t ws_size,
                              hipStream_t stream) {
    const float* x  = (const float*)d_in[0];
    const int*   ei = (const int*)d_in[1];
    const float* W1 = (const float*)d_in[2];
    const float* b1 = (const float*)d_in[3];
    const float* W2 = (const float*)d_in[4];
    const float* b2 = (const float*)d_in[5];
    float* out = (float*)d_out;

    char* ws = (char*)d_ws;
    int*   deg       = (int*)(ws + 0);                       // 400 KB
    int*   row_start = (int*)(ws + 512 * 1024);              // 400 KB + 4
    float* dinv      = (float*)(ws + 1024 * 1024);           // 400 KB
    int*   flag      = (int*)(ws + 1536 * 1024);             // 4 B
    int*   partial   = (int*)(ws + 1540 * 1024);             // 392 B
    int*   csr       = (int*)(ws + 2ull * 1024 * 1024);      // 6.4 MB  [fill..agg2]
    float* h1        = (float*)(ws + 9ull * 1024 * 1024);    // 25.6 MB [fused..agg1_k]
    v2i*   packed    = (v2i*)(ws + 35ull * 1024 * 1024);     // 12.8 MB [fused..fill]
    float* agg1      = (float*)(ws + 35ull * 1024 * 1024);   // 25.6 MB [agg1_k..gemm2]
                                                             //   aliases packed (dead)
    float* h2        = h1;   // alias: h1 dead after agg1_k  [gemm2..agg2]

    detect_k<<<1, 64, 0, stream>>>(ei, flag);
    (void)hipMemsetAsync(deg, 0, NN * sizeof(int), stream);
    // count (atomic-pipe-bound) || gemm1 (VALU-bound) overlapped in one dispatch
    fused_k<<<NB_COUNT + NB_GEMM1, 256, 0, stream>>>(ei, flag, deg, packed, x, W1, h1);
    dinv_k<<<(NN + 255) / 256, 256, 0, stream>>>(deg, dinv);
    scan_sum_k<<<NB_SCAN, 256, 0, stream>>>(deg, partial);
    scan_part_k<<<1, 128, 0, stream>>>(partial);
    scan_out_k<<<NB_SCAN, 256, 0, stream>>>(deg, partial, row_start);
    for (int sw = 0; sw < NSWEEP; sw++)
        fill_k<<<(NE + 255) / 256, 256, 0, stream>>>(packed, row_start, csr,
                                                     sw * SWEEP_W, (sw + 1) * SWEEP_W);

    agg1_k<<<(NN + 3) / 4, 256, 0, stream>>>(csr, row_start, h1, dinv, b1, agg1);
    gemm2_k<<<(NN + 191) / 192, 192, 0, stream>>>(agg1, W2, h2);
    agg2_k<<<(NN + 15) / 16, 256, 0, stream>>>(csr, row_start, h2, dinv, b2, out);
}

// Round 8
// 396.288 us; speedup vs baseline: 1.0937x; 1.0042x over previous
//
#include <hip/hip_runtime.h>

#define NN 100000
#define NE 1600000
#define FIN 256
#define FH 64
#define FC 16

#define SCAN_CHUNK 1024
#define NB_SCAN ((NN + SCAN_CHUNK - 1) / SCAN_CHUNK)   // 98
#define NSWEEP 2
#define SWEEP_W ((NN + NSWEEP - 1) / NSWEEP)           // 50000
#define NB_COUNT ((NE + 255) / 256)                    // 6250
#define NB_GEMM1 ((NN + 63) / 64)                      // 1563

typedef int v2i __attribute__((ext_vector_type(2)));

// ---- edge-index dtype robustness: int64 vs int32 detection -----------------
__global__ void detect_k(const int* __restrict__ ei, int* __restrict__ flag) {
    if (threadIdx.x == 0 && blockIdx.x == 0) {
        int z = (ei[1] == 0) & (ei[3] == 0) & (ei[5] == 0) & (ei[7] == 0);
        *flag = z;   // 1 => int64 layout, 0 => int32 layout
    }
}

__device__ __forceinline__ int eidx(const int* __restrict__ ei, int f, int pos) {
    return f ? ei[2 * pos] : ei[pos];
}

// ---- FUSED: count+rank+pack (blocks < NB_COUNT) || GEMM1 (rest) ------------
// BK=32 -> LDS 16.9 KB -> 8 blocks/CU so count blocks keep full wave
// parallelism for the memory-side atomic pipe (8 atomics/cy chip floor).
__global__ __launch_bounds__(256, 8) void fused_k(const int* __restrict__ ei,
                                                  const int* __restrict__ flag,
                                                  int* __restrict__ deg,
                                                  v2i* __restrict__ packed,
                                                  const float* __restrict__ x,
                                                  const float* __restrict__ W,
                                                  float* __restrict__ h) {
    __shared__ float As[32][68];   // [k][m] transposed, stride 68 (b128-aligned)
    __shared__ float Bs[32][64];
    if (blockIdx.x < NB_COUNT) {
        int e = blockIdx.x * 256 + threadIdx.x;
        if (e >= NE) return;
        int f = *flag;
        int s = eidx(ei, f, e);
        int d = eidx(ei, f, NE + e);
        int r = atomicAdd(&deg[d], 1);
        v2i p; p.x = s; p.y = d | (r << 17);   // dst<2^17, rank<2^12
        packed[e] = p;
        return;
    }
    const int t = threadIdx.x;
    const int r0 = (blockIdx.x - NB_COUNT) * 64;
    const int tx4 = (t & 15) * 4;
    const int ty4 = (t >> 4) * 4;
    // x staging: kf = (t&7)*4, row = t>>3 (0..31), i adds 32
    const int xkf = (t & 7) * 4;
    const int xrow = t >> 3;
    // W staging: col4 = (t&15)*4, krow = t>>4 (0..15), i adds 16
    const int wcol = (t & 15) * 4;
    const int wrow = t >> 4;

    float acc[4][4] = {};

    for (int k0 = 0; k0 < FIN; k0 += 32) {
        #pragma unroll
        for (int i = 0; i < 2; i++) {
            int row = xrow + 32 * i;             // 0..63
            int gr = r0 + row;
            float4 v = make_float4(0.f, 0.f, 0.f, 0.f);
            if (gr < NN) v = *(const float4*)&x[gr * FIN + k0 + xkf];
            As[xkf + 0][row] = v.x;
            As[xkf + 1][row] = v.y;
            As[xkf + 2][row] = v.z;
            As[xkf + 3][row] = v.w;
            int kr = wrow + 16 * i;              // 0..31
            float4 w = *(const float4*)&W[(k0 + kr) * FH + wcol];
            *(float4*)&Bs[kr][wcol] = w;
        }
        __syncthreads();
        #pragma unroll 8
        for (int kk = 0; kk < 32; kk++) {
            float4 a = *(const float4*)&As[kk][ty4];
            float4 b = *(const float4*)&Bs[kk][tx4];
            float av[4] = {a.x, a.y, a.z, a.w};
            float bv[4] = {b.x, b.y, b.z, b.w};
            #pragma unroll
            for (int i2 = 0; i2 < 4; i2++)
                #pragma unroll
                for (int j2 = 0; j2 < 4; j2++)
                    acc[i2][j2] = fmaf(av[i2], bv[j2], acc[i2][j2]);
        }
        __syncthreads();
    }
    #pragma unroll
    for (int i2 = 0; i2 < 4; i2++) {
        int r = r0 + ty4 + i2;
        if (r < NN)
            *(float4*)&h[r * FH + tx4] =
                make_float4(acc[i2][0], acc[i2][1], acc[i2][2], acc[i2][3]);
    }
}

// ---- scan pass 1 (+ fused dinv): per-block sums ----------------------------
__global__ __launch_bounds__(256) void scan_sum_k(const int* __restrict__ deg,
                                                  int* __restrict__ partial,
                                                  float* __restrict__ dinv) {
    __shared__ int red[256];
    int b = blockIdx.x, t = threadIdx.x;
    int base = b * SCAN_CHUNK + t * 4;
    int s = 0;
    #pragma unroll
    for (int i = 0; i < 4; i++) {
        int idx = base + i;
        if (idx < NN) {
            int dv = deg[idx];
            s += dv;
            dinv[idx] = rsqrtf((float)(dv + 1));   // +1 self-loop
        }
    }
    red[t] = s;
    __syncthreads();
    for (int off = 128; off > 0; off >>= 1) {
        if (t < off) red[t] += red[t + off];
        __syncthreads();
    }
    if (t == 0) partial[b] = red[0];
}

// ---- pass 2: single small block exclusive-scans the partials ---------------
__global__ __launch_bounds__(128) void scan_part_k(int* __restrict__ partial) {
    __shared__ int s[128];
    int t = threadIdx.x;
    int v = (t < NB_SCAN) ? partial[t] : 0;
    s[t] = v; __syncthreads();
    for (int off = 1; off < 128; off <<= 1) {
        int u = (t >= off) ? s[t - off] : 0;
        __syncthreads();
        s[t] += u;
        __syncthreads();
    }
    if (t < NB_SCAN) partial[t] = s[t] - v;   // exclusive
}

// ---- pass 3: per-block local scan + offset -> row_start --------------------
__global__ __launch_bounds__(256) void scan_out_k(const int* __restrict__ deg,
                                                  const int* __restrict__ partial,
                                                  int* __restrict__ row_start) {
    __shared__ int s[256];
    int b = blockIdx.x, t = threadIdx.x;
    int base = b * SCAN_CHUNK + t * 4;
    int v[4]; int sum = 0;
    #pragma unroll
    for (int i = 0; i < 4; i++) {
        int idx = base + i;
        v[i] = (idx < NN) ? deg[idx] : 0;
        sum += v[i];
    }
    s[t] = sum; __syncthreads();
    for (int off = 1; off < 256; off <<= 1) {
        int u = (t >= off) ? s[t - off] : 0;
        __syncthreads();
        s[t] += u;
        __syncthreads();
    }
    int run = partial[b] + s[t] - sum;
    #pragma unroll
    for (int i = 0; i < 4; i++) {
        int idx = base + i;
        if (idx < NN) {
            row_start[idx] = run;
            run += v[i];
            if (idx == NN - 1) row_start[NN] = run;   // == NE
        }
    }
}

// ---- CSR fill, dst-range sweep: pure store, no atomic ----------------------
__global__ __launch_bounds__(256) void fill_k(const v2i* __restrict__ packed,
                                              const int* __restrict__ row_start,
                                              int* __restrict__ csr,
                                              int lo, int hi) {
    int e = blockIdx.x * 256 + threadIdx.x;
    if (e >= NE) return;
    v2i p = __builtin_nontemporal_load(&packed[e]);   // (src, dst|rank<<17)
    int d = p.y & 0x1FFFF;
    if (d < lo || d >= hi) return;
    int r = ((unsigned)p.y) >> 17;
    csr[row_start[d] + r] = p.x;
}

// ---- FUSED aggregate layer1 + relu + GEMM2 ---------------------------------
// Per wave: node n. agg row (64 feats, lane=feat) in regs, then
// h2[n][0..15] = relu(agg) @ W2 via per-wave LDS transpose + 16-lane dot.
__global__ __launch_bounds__(256) void agg1g_k(const int* __restrict__ csr,
                                               const int* __restrict__ row_start,
                                               const float* __restrict__ h1,
                                               const float* __restrict__ dinv,
                                               const float* __restrict__ b1,
                                               const float* __restrict__ W2,
                                               float* __restrict__ h2) {
    __shared__ float sW2[FH * FC];     // 4 KB, block-shared
    __shared__ float sp[4][FH];        // per-wave relu'd agg row
    const int t = threadIdx.x;
    #pragma unroll
    for (int i = 0; i < 4; i++) sW2[t + 256 * i] = W2[t + 256 * i];
    __syncthreads();

    int wid = t >> 6;
    int n = blockIdx.x * 4 + wid;
    int lane = t & 63;
    if (n >= NN) return;
    int s0 = row_start[n], s1 = row_start[n + 1];
    float acc = 0.f, a0 = 0.f, a1 = 0.f, a2 = 0.f, a3 = 0.f;
    for (int j0 = s0; j0 < s1; j0 += 64) {
        int idx = j0 + lane;
        int sl = 0; float wl = 0.f;
        if (idx < s1) { sl = csr[idx]; wl = dinv[sl]; }
        int cnt = s1 - j0; if (cnt > 64) cnt = 64;
        int j = 0;
        for (; j + 4 <= cnt; j += 4) {
            int   sA = __shfl(sl, j + 0, 64), sB = __shfl(sl, j + 1, 64);
            int   sC = __shfl(sl, j + 2, 64), sD = __shfl(sl, j + 3, 64);
            float wA = __shfl(wl, j + 0, 64), wB = __shfl(wl, j + 1, 64);
            float wC = __shfl(wl, j + 2, 64), wD = __shfl(wl, j + 3, 64);
            float hA = h1[sA * FH + lane];
            float hB = h1[sB * FH + lane];
            float hC = h1[sC * FH + lane];
            float hD = h1[sD * FH + lane];
            a0 = fmaf(hA, wA, a0); a1 = fmaf(hB, wB, a1);
            a2 = fmaf(hC, wC, a2); a3 = fmaf(hD, wD, a3);
        }
        for (; j < cnt; j++) {
            int   s = __shfl(sl, j, 64);
            float w = __shfl(wl, j, 64);
            acc = fmaf(h1[s * FH + lane], w, acc);
        }
    }
    acc += (a0 + a1) + (a2 + a3);
    float dn = dinv[n];
    acc = fmaf(h1[n * FH + lane], dn, acc);
    float p = fmaf(acc, dn, b1[lane]);
    sp[wid][lane] = fmaxf(p, 0.f);     // wave-local LDS; no block barrier needed
    __builtin_amdgcn_s_waitcnt(0);     // drain lgkm within wave
    if (lane < FC) {
        float o = 0.f;
        #pragma unroll 8
        for (int k = 0; k < FH; k++)
            o = fmaf(sp[wid][k], sW2[k * FC + lane], o);
        h2[n * FC + lane] = o;
    }
}

// ---- aggregate layer2: 16-lane subgroup per node, 4-deep MLP ---------------
__global__ __launch_bounds__(256) void agg2_k(const int* __restrict__ csr,
                                              const int* __restrict__ row_start,
                                              const float* __restrict__ h2,
                                              const float* __restrict__ dinv,
                                              const float* __restrict__ b2,
                                              float* __restrict__ out) {
    int n = blockIdx.x * 16 + (threadIdx.x >> 4);
    int l16 = threadIdx.x & 15;
    int base = threadIdx.x & 48;
    if (n >= NN) return;
    int s0 = row_start[n], s1 = row_start[n + 1];
    float acc = 0.f, a0 = 0.f, a1 = 0.f, a2 = 0.f, a3 = 0.f;
    for (int j0 = s0; j0 < s1; j0 += 16) {
        int idx = j0 + l16;
        int sl = 0; float wl = 0.f;
        if (idx < s1) { sl = csr[idx]; wl = dinv[sl]; }
        int cnt = s1 - j0; if (cnt > 16) cnt = 16;
        int j = 0;
        for (; j + 4 <= cnt; j += 4) {
            int   sA = __shfl(sl, base + j + 0, 64), sB = __shfl(sl, base + j + 1, 64);
            int   sC = __shfl(sl, base + j + 2, 64), sD = __shfl(sl, base + j + 3, 64);
            float wA = __shfl(wl, base + j + 0, 64), wB = __shfl(wl, base + j + 1, 64);
            float wC = __shfl(wl, base + j + 2, 64), wD = __shfl(wl, base + j + 3, 64);
            float hA = h2[sA * FC + l16];
            float hB = h2[sB * FC + l16];
            float hC = h2[sC * FC + l16];
            float hD = h2[sD * FC + l16];
            a0 = fmaf(hA, wA, a0); a1 = fmaf(hB, wB, a1);
            a2 = fmaf(hC, wC, a2); a3 = fmaf(hD, wD, a3);
        }
        for (; j < cnt; j++) {
            int   s = __shfl(sl, base + j, 64);
            float w = __shfl(wl, base + j, 64);
            acc = fmaf(h2[s * FC + l16], w, acc);
        }
    }
    acc += (a0 + a1) + (a2 + a3);
    float dn = dinv[n];
    acc = fmaf(h2[n * FC + l16], dn, acc);
    out[n * FC + l16] = fmaf(acc, dn, b2[l16]);
}

extern "C" void kernel_launch(void* const* d_in, const int* in_sizes, int n_in,
                              void* d_out, int out_size, void* d_ws, size_t ws_size,
                              hipStream_t stream) {
    const float* x  = (const float*)d_in[0];
    const int*   ei = (const int*)d_in[1];
    const float* W1 = (const float*)d_in[2];
    const float* b1 = (const float*)d_in[3];
    const float* W2 = (const float*)d_in[4];
    const float* b2 = (const float*)d_in[5];
    float* out = (float*)d_out;

    char* ws = (char*)d_ws;
    int*   deg       = (int*)(ws + 0);                       // 400 KB
    int*   row_start = (int*)(ws + 512 * 1024);              // 400 KB + 4
    float* dinv      = (float*)(ws + 1024 * 1024);           // 400 KB
    int*   flag      = (int*)(ws + 1536 * 1024);             // 4 B
    int*   partial   = (int*)(ws + 1540 * 1024);             // 392 B
    int*   csr       = (int*)(ws + 2ull * 1024 * 1024);      // 6.4 MB  [fill..agg2]
    float* h1        = (float*)(ws + 9ull * 1024 * 1024);    // 25.6 MB [fused..agg1g]
    v2i*   packed    = (v2i*)(ws + 35ull * 1024 * 1024);     // 12.8 MB [fused..fill]
    float* h2        = (float*)(ws + 35ull * 1024 * 1024);   // 6.4 MB  [agg1g..agg2]
                                                             //   aliases packed (dead)

    detect_k<<<1, 64, 0, stream>>>(ei, flag);
    (void)hipMemsetAsync(deg, 0, NN * sizeof(int), stream);
    // count (atomic-pipe-bound) || gemm1 (VALU-bound) overlapped in one dispatch
    fused_k<<<NB_COUNT + NB_GEMM1, 256, 0, stream>>>(ei, flag, deg, packed, x, W1, h1);
    scan_sum_k<<<NB_SCAN, 256, 0, stream>>>(deg, partial, dinv);
    scan_part_k<<<1, 128, 0, stream>>>(partial);
    scan_out_k<<<NB_SCAN, 256, 0, stream>>>(deg, partial, row_start);
    for (int sw = 0; sw < NSWEEP; sw++)
        fill_k<<<(NE + 255) / 256, 256, 0, stream>>>(packed, row_start, csr,
                                                     sw * SWEEP_W, (sw + 1) * SWEEP_W);

    agg1g_k<<<(NN + 3) / 4, 256, 0, stream>>>(csr, row_start, h1, dinv, b1, W2, h2);
    agg2_k<<<(NN + 15) / 16, 256, 0, stream>>>(csr, row_start, h2, dinv, b2, out);
}

// Round 9
// 361.913 us; speedup vs baseline: 1.1975x; 1.0950x over previous
//
#include <hip/hip_runtime.h>

#define NN 100000
#define NE 1600000
#define FIN 256
#define FH 64
#define FC 16

#define SCAN_CHUNK 1024
#define NB_SCAN ((NN + SCAN_CHUNK - 1) / SCAN_CHUNK)   // 98
#define NSWEEP 2
#define SWEEP_W ((NN + NSWEEP - 1) / NSWEEP)           // 50000
#define NB_COUNT ((NE + 255) / 256)                    // 6250
#define NB_GEMM1 ((NN + 63) / 64)                      // 1563
#define NB_FUSED (5 * NB_GEMM1)                        // 7815: every 5th block = gemm

typedef int v2i __attribute__((ext_vector_type(2)));

__device__ __forceinline__ float4 fma4(float4 v, float w, float4 a) {
    a.x = fmaf(v.x, w, a.x); a.y = fmaf(v.y, w, a.y);
    a.z = fmaf(v.z, w, a.z); a.w = fmaf(v.w, w, a.w);
    return a;
}
__device__ __forceinline__ float4 xor_add4(float4 r, int m) {
    r.x += __shfl_xor(r.x, m, 64); r.y += __shfl_xor(r.y, m, 64);
    r.z += __shfl_xor(r.z, m, 64); r.w += __shfl_xor(r.w, m, 64);
    return r;
}

// ---- edge-index dtype robustness: int64 vs int32 detection -----------------
__global__ void detect_k(const int* __restrict__ ei, int* __restrict__ flag) {
    if (threadIdx.x == 0 && blockIdx.x == 0) {
        int z = (ei[1] == 0) & (ei[3] == 0) & (ei[5] == 0) & (ei[7] == 0);
        *flag = z;   // 1 => int64 layout, 0 => int32 layout
    }
}

__device__ __forceinline__ int eidx(const int* __restrict__ ei, int f, int pos) {
    return f ? ei[2 * pos] : ei[pos];
}

// ---- FUSED: count+rank+pack || GEMM1, roles INTERLEAVED (b%5==4 -> gemm) ---
// Interleaving keeps count (atomic-floor-bound, VALU idle) and gemm blocks
// co-resident from dispatch start -> gemm hides under the atomic floor.
__global__ __launch_bounds__(256, 8) void fused_k(const int* __restrict__ ei,
                                                  const int* __restrict__ flag,
                                                  int* __restrict__ deg,
                                                  v2i* __restrict__ packed,
                                                  const float* __restrict__ x,
                                                  const float* __restrict__ W,
                                                  float* __restrict__ h) {
    __shared__ float As[32][68];
    __shared__ float Bs[32][64];
    const int b = blockIdx.x;
    if ((b % 5) != 4) {                       // ---- count role ----
        int cb = (b / 5) * 4 + (b % 5);       // 0..6251 unique
        if (cb >= NB_COUNT) return;
        int e = cb * 256 + threadIdx.x;
        if (e >= NE) return;
        int f = *flag;
        int s = eidx(ei, f, e);
        int d = eidx(ei, f, NE + e);
        int r = atomicAdd(&deg[d], 1);
        v2i p; p.x = s; p.y = d | (r << 17);  // dst<2^17, rank<2^12
        packed[e] = p;
        return;
    }
    // ---- GEMM1 role: h[NN][64] = x[NN][256] @ W[256][64], 64x64 tile, BK=32
    const int t = threadIdx.x;
    const int r0 = (b / 5) * 64;
    const int tx4 = (t & 15) * 4;
    const int ty4 = (t >> 4) * 4;
    const int xkf = (t & 7) * 4;
    const int xrow = t >> 3;
    const int wcol = (t & 15) * 4;
    const int wrow = t >> 4;

    float acc[4][4] = {};

    for (int k0 = 0; k0 < FIN; k0 += 32) {
        #pragma unroll
        for (int i = 0; i < 2; i++) {
            int row = xrow + 32 * i;
            int gr = r0 + row;
            float4 v = make_float4(0.f, 0.f, 0.f, 0.f);
            if (gr < NN) v = *(const float4*)&x[gr * FIN + k0 + xkf];
            As[xkf + 0][row] = v.x;
            As[xkf + 1][row] = v.y;
            As[xkf + 2][row] = v.z;
            As[xkf + 3][row] = v.w;
            int kr = wrow + 16 * i;
            float4 w = *(const float4*)&W[(k0 + kr) * FH + wcol];
            *(float4*)&Bs[kr][wcol] = w;
        }
        __syncthreads();
        #pragma unroll 8
        for (int kk = 0; kk < 32; kk++) {
            float4 a = *(const float4*)&As[kk][ty4];
            float4 bq = *(const float4*)&Bs[kk][tx4];
            float av[4] = {a.x, a.y, a.z, a.w};
            float bv[4] = {bq.x, bq.y, bq.z, bq.w};
            #pragma unroll
            for (int i2 = 0; i2 < 4; i2++)
                #pragma unroll
                for (int j2 = 0; j2 < 4; j2++)
                    acc[i2][j2] = fmaf(av[i2], bv[j2], acc[i2][j2]);
        }
        __syncthreads();
    }
    #pragma unroll
    for (int i2 = 0; i2 < 4; i2++) {
        int r = r0 + ty4 + i2;
        if (r < NN)
            *(float4*)&h[r * FH + tx4] =
                make_float4(acc[i2][0], acc[i2][1], acc[i2][2], acc[i2][3]);
    }
}

// ---- scan pass 1 (+ fused dinv): per-block sums ----------------------------
__global__ __launch_bounds__(256) void scan_sum_k(const int* __restrict__ deg,
                                                  int* __restrict__ partial,
                                                  float* __restrict__ dinv) {
    __shared__ int red[256];
    int b = blockIdx.x, t = threadIdx.x;
    int base = b * SCAN_CHUNK + t * 4;
    int s = 0;
    #pragma unroll
    for (int i = 0; i < 4; i++) {
        int idx = base + i;
        if (idx < NN) {
            int dv = deg[idx];
            s += dv;
            dinv[idx] = rsqrtf((float)(dv + 1));   // +1 self-loop
        }
    }
    red[t] = s;
    __syncthreads();
    for (int off = 128; off > 0; off >>= 1) {
        if (t < off) red[t] += red[t + off];
        __syncthreads();
    }
    if (t == 0) partial[b] = red[0];
}

// ---- pass 2: single small block exclusive-scans the partials ---------------
__global__ __launch_bounds__(128) void scan_part_k(int* __restrict__ partial) {
    __shared__ int s[128];
    int t = threadIdx.x;
    int v = (t < NB_SCAN) ? partial[t] : 0;
    s[t] = v; __syncthreads();
    for (int off = 1; off < 128; off <<= 1) {
        int u = (t >= off) ? s[t - off] : 0;
        __syncthreads();
        s[t] += u;
        __syncthreads();
    }
    if (t < NB_SCAN) partial[t] = s[t] - v;   // exclusive
}

// ---- pass 3: per-block local scan + offset -> row_start --------------------
__global__ __launch_bounds__(256) void scan_out_k(const int* __restrict__ deg,
                                                  const int* __restrict__ partial,
                                                  int* __restrict__ row_start) {
    __shared__ int s[256];
    int b = blockIdx.x, t = threadIdx.x;
    int base = b * SCAN_CHUNK + t * 4;
    int v[4]; int sum = 0;
    #pragma unroll
    for (int i = 0; i < 4; i++) {
        int idx = base + i;
        v[i] = (idx < NN) ? deg[idx] : 0;
        sum += v[i];
    }
    s[t] = sum; __syncthreads();
    for (int off = 1; off < 256; off <<= 1) {
        int u = (t >= off) ? s[t - off] : 0;
        __syncthreads();
        s[t] += u;
        __syncthreads();
    }
    int run = partial[b] + s[t] - sum;
    #pragma unroll
    for (int i = 0; i < 4; i++) {
        int idx = base + i;
        if (idx < NN) {
            row_start[idx] = run;
            run += v[i];
            if (idx == NN - 1) row_start[NN] = run;   // == NE
        }
    }
}

// ---- CSR fill, dst-range sweep: pure store, no atomic ----------------------
__global__ __launch_bounds__(256) void fill_k(const v2i* __restrict__ packed,
                                              const int* __restrict__ row_start,
                                              int* __restrict__ csr,
                                              int lo, int hi) {
    int e = blockIdx.x * 256 + threadIdx.x;
    if (e >= NE) return;
    v2i p = __builtin_nontemporal_load(&packed[e]);   // (src, dst|rank<<17)
    int d = p.y & 0x1FFFF;
    if (d < lo || d >= hi) return;
    int r = ((unsigned)p.y) >> 17;
    csr[row_start[d] + r] = p.x;
}

// ---- FUSED agg1 + relu + GEMM2, float4 gather ------------------------------
// Wave = node n. 4 edge-subgroups (sg) x 16 feature-quads (fl): one float4
// load covers 4 edges/instruction; 2-deep unroll -> 8 edges in flight.
__global__ __launch_bounds__(256) void agg1g_k(const int* __restrict__ csr,
                                               const int* __restrict__ row_start,
                                               const float* __restrict__ h1,
                                               const float* __restrict__ dinv,
                                               const float* __restrict__ b1,
                                               const float* __restrict__ W2,
                                               float* __restrict__ h2) {
    __shared__ float sW2[FH * FC];     // 4 KB
    __shared__ float sp[4][FH];        // per-wave relu'd agg row
    const int t = threadIdx.x;
    #pragma unroll
    for (int i = 0; i < 4; i++) sW2[t + 256 * i] = W2[t + 256 * i];
    __syncthreads();

    int wid = t >> 6;
    int n = blockIdx.x * 4 + wid;
    int lane = t & 63;
    if (n >= NN) return;
    int sg = lane >> 4;        // edge slot 0..3
    int fl = lane & 15;        // feature quad 0..15
    int s0 = row_start[n], s1 = row_start[n + 1];
    float4 A = make_float4(0.f, 0.f, 0.f, 0.f);
    float4 B = make_float4(0.f, 0.f, 0.f, 0.f);
    for (int j0 = s0; j0 < s1; j0 += 64) {
        int idx = j0 + lane;
        int sl = 0; float wl = 0.f;
        if (idx < s1) { sl = csr[idx]; wl = dinv[sl]; }
        int cnt = s1 - j0; if (cnt > 64) cnt = 64;
        int j = 0;
        for (; j + 8 <= cnt; j += 8) {
            int   eA = __shfl(sl, j + sg, 64);
            float wA = __shfl(wl, j + sg, 64);
            int   eB = __shfl(sl, j + 4 + sg, 64);
            float wB = __shfl(wl, j + 4 + sg, 64);
            float4 vA = *(const float4*)&h1[eA * FH + fl * 4];
            float4 vB = *(const float4*)&h1[eB * FH + fl * 4];
            A = fma4(vA, wA, A);
            B = fma4(vB, wB, B);
        }
        if (j + 4 <= cnt) {
            int   eA = __shfl(sl, j + sg, 64);
            float wA = __shfl(wl, j + sg, 64);
            float4 vA = *(const float4*)&h1[eA * FH + fl * 4];
            A = fma4(vA, wA, A);
            j += 4;
        }
        int rem = cnt - j;
        if (rem > 0) {                      // 1..3 edges, predicate extra slots
            int jj = j + (sg < rem ? sg : 0);
            int   eA = __shfl(sl, jj, 64);
            float wA = __shfl(wl, jj, 64);
            if (sg >= rem) wA = 0.f;
            float4 vA = *(const float4*)&h1[eA * FH + fl * 4];
            A = fma4(vA, wA, A);
        }
    }
    float4 r = make_float4(A.x + B.x, A.y + B.y, A.z + B.z, A.w + B.w);
    r = xor_add4(r, 16);
    r = xor_add4(r, 32);                    // all lanes hold full quad sum
    if (sg == 0) {
        float dn = dinv[n];
        float4 self = *(const float4*)&h1[n * FH + fl * 4];
        float4 bq = *(const float4*)&b1[fl * 4];
        float4 p;
        p.x = fmaxf(fmaf(fmaf(self.x, dn, r.x), dn, bq.x), 0.f);
        p.y = fmaxf(fmaf(fmaf(self.y, dn, r.y), dn, bq.y), 0.f);
        p.z = fmaxf(fmaf(fmaf(self.z, dn, r.z), dn, bq.z), 0.f);
        p.w = fmaxf(fmaf(fmaf(self.w, dn, r.w), dn, bq.w), 0.f);
        *(float4*)&sp[wid][fl * 4] = p;     // wave-local LDS
    }
    __builtin_amdgcn_s_waitcnt(0);          // drain lgkm within wave
    if (lane < FC) {
        float o = 0.f;
        #pragma unroll 8
        for (int k = 0; k < FH; k++)
            o = fmaf(sp[wid][k], sW2[k * FC + lane], o);
        h2[n * FC + lane] = o;
    }
}

// ---- agg layer2, float4 gather: 16-lane subgroup/node, 4 edges in flight ---
// Within subgroup: q = edge slot (0..3), c = feature quad (0..3).
__global__ __launch_bounds__(256) void agg2_k(const int* __restrict__ csr,
                                              const int* __restrict__ row_start,
                                              const float* __restrict__ h2,
                                              const float* __restrict__ dinv,
                                              const float* __restrict__ b2,
                                              float* __restrict__ out) {
    const int t = threadIdx.x;
    int n = blockIdx.x * 16 + (t >> 4);
    int l16 = t & 15;
    int base = t & 48;          // subgroup base lane in wave
    int q = (t >> 2) & 3;       // edge slot
    int c = t & 3;              // feature quad
    if (n >= NN) return;
    int s0 = row_start[n], s1 = row_start[n + 1];
    float4 A = make_float4(0.f, 0.f, 0.f, 0.f);
    float4 B = make_float4(0.f, 0.f, 0.f, 0.f);
    for (int j0 = s0; j0 < s1; j0 += 16) {
        int idx = j0 + l16;
        int sl = 0; float wl = 0.f;
        if (idx < s1) { sl = csr[idx]; wl = dinv[sl]; }
        int cnt = s1 - j0; if (cnt > 16) cnt = 16;
        int j = 0;
        for (; j + 8 <= cnt; j += 8) {
            int   eA = __shfl(sl, base + j + q, 64);
            float wA = __shfl(wl, base + j + q, 64);
            int   eB = __shfl(sl, base + j + 4 + q, 64);
            float wB = __shfl(wl, base + j + 4 + q, 64);
            float4 vA = *(const float4*)&h2[eA * FC + c * 4];
            float4 vB = *(const float4*)&h2[eB * FC + c * 4];
            A = fma4(vA, wA, A);
            B = fma4(vB, wB, B);
        }
        if (j + 4 <= cnt) {
            int   eA = __shfl(sl, base + j + q, 64);
            float wA = __shfl(wl, base + j + q, 64);
            float4 vA = *(const float4*)&h2[eA * FC + c * 4];
            A = fma4(vA, wA, A);
            j += 4;
        }
        int rem = cnt - j;
        if (rem > 0) {
            int jj = base + j + (q < rem ? q : 0);
            int   eA = __shfl(sl, jj, 64);
            float wA = __shfl(wl, jj, 64);
            if (q >= rem) wA = 0.f;
            float4 vA = *(const float4*)&h2[eA * FC + c * 4];
            A = fma4(vA, wA, A);
        }
    }
    float4 r = make_float4(A.x + B.x, A.y + B.y, A.z + B.z, A.w + B.w);
    r = xor_add4(r, 4);
    r = xor_add4(r, 8);                     // reduce across q within subgroup
    if (q == 0) {
        float dn = dinv[n];
        float4 self = *(const float4*)&h2[n * FC + c * 4];
        float4 bq = *(const float4*)&b2[c * 4];
        float4 p;
        p.x = fmaf(fmaf(self.x, dn, r.x), dn, bq.x);
        p.y = fmaf(fmaf(self.y, dn, r.y), dn, bq.y);
        p.z = fmaf(fmaf(self.z, dn, r.z), dn, bq.z);
        p.w = fmaf(fmaf(self.w, dn, r.w), dn, bq.w);
        *(float4*)&out[n * FC + c * 4] = p;
    }
}

extern "C" void kernel_launch(void* const* d_in, const int* in_sizes, int n_in,
                              void* d_out, int out_size, void* d_ws, size_t ws_size,
                              hipStream_t stream) {
    const float* x  = (const float*)d_in[0];
    const int*   ei = (const int*)d_in[1];
    const float* W1 = (const float*)d_in[2];
    const float* b1 = (const float*)d_in[3];
    const float* W2 = (const float*)d_in[4];
    const float* b2 = (const float*)d_in[5];
    float* out = (float*)d_out;

    char* ws = (char*)d_ws;
    int*   deg       = (int*)(ws + 0);                       // 400 KB
    int*   row_start = (int*)(ws + 512 * 1024);              // 400 KB + 4
    float* dinv      = (float*)(ws + 1024 * 1024);           // 400 KB
    int*   flag      = (int*)(ws + 1536 * 1024);             // 4 B
    int*   partial   = (int*)(ws + 1540 * 1024);             // 392 B
    int*   csr       = (int*)(ws + 2ull * 1024 * 1024);      // 6.4 MB  [fill..agg2]
    float* h1        = (float*)(ws + 9ull * 1024 * 1024);    // 25.6 MB [fused..agg1g]
    v2i*   packed    = (v2i*)(ws + 35ull * 1024 * 1024);     // 12.8 MB [fused..fill]
    float* h2        = (float*)(ws + 35ull * 1024 * 1024);   // 6.4 MB  [agg1g..agg2]
                                                             //   aliases packed (dead)

    detect_k<<<1, 64, 0, stream>>>(ei, flag);
    (void)hipMemsetAsync(deg, 0, NN * sizeof(int), stream);
    fused_k<<<NB_FUSED, 256, 0, stream>>>(ei, flag, deg, packed, x, W1, h1);
    scan_sum_k<<<NB_SCAN, 256, 0, stream>>>(deg, partial, dinv);
    scan_part_k<<<1, 128, 0, stream>>>(partial);
    scan_out_k<<<NB_SCAN, 256, 0, stream>>>(deg, partial, row_start);
    for (int sw = 0; sw < NSWEEP; sw++)
        fill_k<<<(NE + 255) / 256, 256, 0, stream>>>(packed, row_start, csr,
                                                     sw * SWEEP_W, (sw + 1) * SWEEP_W);

    agg1g_k<<<(NN + 3) / 4, 256, 0, stream>>>(csr, row_start, h1, dinv, b1, W2, h2);
    agg2_k<<<(NN + 15) / 16, 256, 0, stream>>>(csr, row_start, h2, dinv, b2, out);
}

// Round 10
// 360.172 us; speedup vs baseline: 1.2033x; 1.0048x over previous
//
#include <hip/hip_runtime.h>

#define NN 100000
#define NE 1600000
#define FIN 256
#define FH 64
#define FC 16

#define SCAN_CHUNK 1024
#define NB_SCAN ((NN + SCAN_CHUNK - 1) / SCAN_CHUNK)   // 98
#define NB_COUNT ((NE + 255) / 256)                    // 6250
#define NB_GEMM1 ((NN + 63) / 64)                      // 1563
#define NB_FUSED (5 * NB_GEMM1)                        // 7815: every 5th block = gemm

typedef int v2i __attribute__((ext_vector_type(2)));

__device__ __forceinline__ float4 fma4(float4 v, float w, float4 a) {
    a.x = fmaf(v.x, w, a.x); a.y = fmaf(v.y, w, a.y);
    a.z = fmaf(v.z, w, a.z); a.w = fmaf(v.w, w, a.w);
    return a;
}
__device__ __forceinline__ float4 add4(float4 a, float4 v) {
    a.x += v.x; a.y += v.y; a.z += v.z; a.w += v.w;
    return a;
}
__device__ __forceinline__ float4 xor_add4(float4 r, int m) {
    r.x += __shfl_xor(r.x, m, 64); r.y += __shfl_xor(r.y, m, 64);
    r.z += __shfl_xor(r.z, m, 64); r.w += __shfl_xor(r.w, m, 64);
    return r;
}

// ---- edge-index dtype robustness: int64 vs int32 detection -----------------
__global__ void detect_k(const int* __restrict__ ei, int* __restrict__ flag) {
    if (threadIdx.x == 0 && blockIdx.x == 0) {
        int z = (ei[1] == 0) & (ei[3] == 0) & (ei[5] == 0) & (ei[7] == 0);
        *flag = z;   // 1 => int64 layout, 0 => int32 layout
    }
}

__device__ __forceinline__ int eidx(const int* __restrict__ ei, int f, int pos) {
    return f ? ei[2 * pos] : ei[pos];
}

// ---- FUSED: count+rank+pack || GEMM1, roles INTERLEAVED (b%5==4 -> gemm) ---
__global__ __launch_bounds__(256, 8) void fused_k(const int* __restrict__ ei,
                                                  const int* __restrict__ flag,
                                                  int* __restrict__ deg,
                                                  v2i* __restrict__ packed,
                                                  const float* __restrict__ x,
                                                  const float* __restrict__ W,
                                                  float* __restrict__ h) {
    __shared__ float As[32][68];
    __shared__ float Bs[32][64];
    const int b = blockIdx.x;
    if ((b % 5) != 4) {                       // ---- count role ----
        int cb = (b / 5) * 4 + (b % 5);
        if (cb >= NB_COUNT) return;
        int e = cb * 256 + threadIdx.x;
        if (e >= NE) return;
        int f = *flag;
        int s = eidx(ei, f, e);
        int d = eidx(ei, f, NE + e);
        int r = atomicAdd(&deg[d], 1);
        v2i p; p.x = s; p.y = d | (r << 17);  // dst<2^17, rank<2^12
        packed[e] = p;
        return;
    }
    // ---- GEMM1 role: h[NN][64] = x[NN][256] @ W[256][64], 64x64 tile, BK=32
    const int t = threadIdx.x;
    const int r0 = (b / 5) * 64;
    const int tx4 = (t & 15) * 4;
    const int ty4 = (t >> 4) * 4;
    const int xkf = (t & 7) * 4;
    const int xrow = t >> 3;
    const int wcol = (t & 15) * 4;
    const int wrow = t >> 4;

    float acc[4][4] = {};

    for (int k0 = 0; k0 < FIN; k0 += 32) {
        #pragma unroll
        for (int i = 0; i < 2; i++) {
            int row = xrow + 32 * i;
            int gr = r0 + row;
            float4 v = make_float4(0.f, 0.f, 0.f, 0.f);
            if (gr < NN) v = *(const float4*)&x[gr * FIN + k0 + xkf];
            As[xkf + 0][row] = v.x;
            As[xkf + 1][row] = v.y;
            As[xkf + 2][row] = v.z;
            As[xkf + 3][row] = v.w;
            int kr = wrow + 16 * i;
            float4 w = *(const float4*)&W[(k0 + kr) * FH + wcol];
            *(float4*)&Bs[kr][wcol] = w;
        }
        __syncthreads();
        #pragma unroll 8
        for (int kk = 0; kk < 32; kk++) {
            float4 a = *(const float4*)&As[kk][ty4];
            float4 bq = *(const float4*)&Bs[kk][tx4];
            float av[4] = {a.x, a.y, a.z, a.w};
            float bv[4] = {bq.x, bq.y, bq.z, bq.w};
            #pragma unroll
            for (int i2 = 0; i2 < 4; i2++)
                #pragma unroll
                for (int j2 = 0; j2 < 4; j2++)
                    acc[i2][j2] = fmaf(av[i2], bv[j2], acc[i2][j2]);
        }
        __syncthreads();
    }
    #pragma unroll
    for (int i2 = 0; i2 < 4; i2++) {
        int r = r0 + ty4 + i2;
        if (r < NN)
            *(float4*)&h[r * FH + tx4] =
                make_float4(acc[i2][0], acc[i2][1], acc[i2][2], acc[i2][3]);
    }
}

// ---- scan pass 1 (+ fused dinv): per-block sums ----------------------------
__global__ __launch_bounds__(256) void scan_sum_k(const int* __restrict__ deg,
                                                  int* __restrict__ partial,
                                                  float* __restrict__ dinv) {
    __shared__ int red[256];
    int b = blockIdx.x, t = threadIdx.x;
    int base = b * SCAN_CHUNK + t * 4;
    int s = 0;
    #pragma unroll
    for (int i = 0; i < 4; i++) {
        int idx = base + i;
        if (idx < NN) {
            int dv = deg[idx];
            s += dv;
            dinv[idx] = rsqrtf((float)(dv + 1));   // +1 self-loop
        }
    }
    red[t] = s;
    __syncthreads();
    for (int off = 128; off > 0; off >>= 1) {
        if (t < off) red[t] += red[t + off];
        __syncthreads();
    }
    if (t == 0) partial[b] = red[0];
}

// ---- pre-scale h1 rows by dinv: h1'[n] = dinv[n]*h1[n] ---------------------
// Removes per-edge dinv gather + weight shuffles from agg1g's hot loop.
__global__ __launch_bounds__(256) void scale1_k(float* __restrict__ h1,
                                                const float* __restrict__ dinv) {
    int i = blockIdx.x * 256 + threadIdx.x;     // quad id over NN*16
    if (i >= NN * 16) return;
    int row = i >> 4;
    float d = dinv[row];
    float4 v = *(const float4*)&h1[i * 4];
    v.x *= d; v.y *= d; v.z *= d; v.w *= d;
    *(float4*)&h1[i * 4] = v;
}

// ---- pass 2: single small block exclusive-scans the partials ---------------
__global__ __launch_bounds__(128) void scan_part_k(int* __restrict__ partial) {
    __shared__ int s[128];
    int t = threadIdx.x;
    int v = (t < NB_SCAN) ? partial[t] : 0;
    s[t] = v; __syncthreads();
    for (int off = 1; off < 128; off <<= 1) {
        int u = (t >= off) ? s[t - off] : 0;
        __syncthreads();
        s[t] += u;
        __syncthreads();
    }
    if (t < NB_SCAN) partial[t] = s[t] - v;   // exclusive
}

// ---- pass 3: per-block local scan + offset -> row_start --------------------
__global__ __launch_bounds__(256) void scan_out_k(const int* __restrict__ deg,
                                                  const int* __restrict__ partial,
                                                  int* __restrict__ row_start) {
    __shared__ int s[256];
    int b = blockIdx.x, t = threadIdx.x;
    int base = b * SCAN_CHUNK + t * 4;
    int v[4]; int sum = 0;
    #pragma unroll
    for (int i = 0; i < 4; i++) {
        int idx = base + i;
        v[i] = (idx < NN) ? deg[idx] : 0;
        sum += v[i];
    }
    s[t] = sum; __syncthreads();
    for (int off = 1; off < 256; off <<= 1) {
        int u = (t >= off) ? s[t - off] : 0;
        __syncthreads();
        s[t] += u;
        __syncthreads();
    }
    int run = partial[b] + s[t] - sum;
    #pragma unroll
    for (int i = 0; i < 4; i++) {
        int idx = base + i;
        if (idx < NN) {
            row_start[idx] = run;
            run += v[i];
            if (idx == NN - 1) row_start[NN] = run;   // == NE
        }
    }
}

// ---- CSR fill: single pass, pure store, no atomic --------------------------
__global__ __launch_bounds__(256) void fill_k(const v2i* __restrict__ packed,
                                              const int* __restrict__ row_start,
                                              int* __restrict__ csr) {
    int e = blockIdx.x * 256 + threadIdx.x;
    if (e >= NE) return;
    v2i p = __builtin_nontemporal_load(&packed[e]);   // (src, dst|rank<<17)
    int d = p.y & 0x1FFFF;
    int r = ((unsigned)p.y) >> 17;
    csr[row_start[d] + r] = p.x;
}

// ---- FUSED agg1 + relu + GEMM2 (h1 prescaled; h2' = dinv*h2 stored) --------
// Wave = node n; 4 edge-subgroups (sg) x 16 feature-quads (fl); 16 edges in
// flight (A..D). Main loop: shfl + float4 load + add only.
__global__ __launch_bounds__(256) void agg1g_k(const int* __restrict__ csr,
                                               const int* __restrict__ row_start,
                                               const float* __restrict__ h1,
                                               const float* __restrict__ dinv,
                                               const float* __restrict__ b1,
                                               const float* __restrict__ W2,
                                               float* __restrict__ h2) {
    __shared__ float sW2[FH * FC];     // 4 KB
    __shared__ float sp[4][FH];        // per-wave relu'd agg row
    const int t = threadIdx.x;
    #pragma unroll
    for (int i = 0; i < 4; i++) sW2[t + 256 * i] = W2[t + 256 * i];
    __syncthreads();

    int wid = t >> 6;
    int n = blockIdx.x * 4 + wid;
    int lane = t & 63;
    if (n >= NN) return;
    int sg = lane >> 4;        // edge slot 0..3
    int fl = lane & 15;        // feature quad 0..15
    int s0 = row_start[n], s1 = row_start[n + 1];
    float4 A = make_float4(0.f, 0.f, 0.f, 0.f);
    float4 B = make_float4(0.f, 0.f, 0.f, 0.f);
    float4 C = make_float4(0.f, 0.f, 0.f, 0.f);
    float4 D = make_float4(0.f, 0.f, 0.f, 0.f);
    for (int j0 = s0; j0 < s1; j0 += 64) {
        int idx = j0 + lane;
        int sl = (idx < s1) ? csr[idx] : 0;
        int cnt = s1 - j0; if (cnt > 64) cnt = 64;
        int j = 0;
        for (; j + 16 <= cnt; j += 16) {
            int eA = __shfl(sl, j + sg, 64);
            int eB = __shfl(sl, j + 4 + sg, 64);
            int eC = __shfl(sl, j + 8 + sg, 64);
            int eD = __shfl(sl, j + 12 + sg, 64);
            float4 vA = *(const float4*)&h1[eA * FH + fl * 4];
            float4 vB = *(const float4*)&h1[eB * FH + fl * 4];
            float4 vC = *(const float4*)&h1[eC * FH + fl * 4];
            float4 vD = *(const float4*)&h1[eD * FH + fl * 4];
            A = add4(A, vA); B = add4(B, vB);
            C = add4(C, vC); D = add4(D, vD);
        }
        if (j + 8 <= cnt) {
            int eA = __shfl(sl, j + sg, 64);
            int eB = __shfl(sl, j + 4 + sg, 64);
            float4 vA = *(const float4*)&h1[eA * FH + fl * 4];
            float4 vB = *(const float4*)&h1[eB * FH + fl * 4];
            A = add4(A, vA); B = add4(B, vB);
            j += 8;
        }
        if (j + 4 <= cnt) {
            int eA = __shfl(sl, j + sg, 64);
            float4 vA = *(const float4*)&h1[eA * FH + fl * 4];
            A = add4(A, vA);
            j += 4;
        }
        int rem = cnt - j;
        if (rem > 0) {                      // 1..3 edges, mask extra slots
            int jj = j + (sg < rem ? sg : 0);
            int eA = __shfl(sl, jj, 64);
            float wA = (sg < rem) ? 1.f : 0.f;
            float4 vA = *(const float4*)&h1[eA * FH + fl * 4];
            A = fma4(vA, wA, A);
        }
    }
    float4 r = add4(add4(A, B), add4(C, D));
    r = xor_add4(r, 16);
    r = xor_add4(r, 32);                    // all lanes hold full quad sum
    float dn = dinv[n];
    if (sg == 0) {
        float4 self = *(const float4*)&h1[n * FH + fl * 4];   // h1' already scaled
        float4 bq = *(const float4*)&b1[fl * 4];
        float4 p;
        p.x = fmaxf(fmaf(r.x + self.x, dn, bq.x), 0.f);
        p.y = fmaxf(fmaf(r.y + self.y, dn, bq.y), 0.f);
        p.z = fmaxf(fmaf(r.z + self.z, dn, bq.z), 0.f);
        p.w = fmaxf(fmaf(r.w + self.w, dn, bq.w), 0.f);
        *(float4*)&sp[wid][fl * 4] = p;     // wave-local LDS
    }
    __builtin_amdgcn_s_waitcnt(0);          // drain lgkm within wave
    if (lane < FC) {
        float o = 0.f;
        #pragma unroll 8
        for (int k = 0; k < FH; k++)
            o = fmaf(sp[wid][k], sW2[k * FC + lane], o);
        h2[n * FC + lane] = o * dn;         // store h2' = dinv*h2
    }
}

// ---- agg layer2 (h2' prescaled): 16-lane subgroup/node, 16 edges in flight -
__global__ __launch_bounds__(256) void agg2_k(const int* __restrict__ csr,
                                              const int* __restrict__ row_start,
                                              const float* __restrict__ h2,
                                              const float* __restrict__ dinv,
                                              const float* __restrict__ b2,
                                              float* __restrict__ out) {
    const int t = threadIdx.x;
    int n = blockIdx.x * 16 + (t >> 4);
    int l16 = t & 15;
    int base = t & 48;          // subgroup base lane in wave
    int q = (t >> 2) & 3;       // edge slot
    int c = t & 3;              // feature quad
    if (n >= NN) return;
    int s0 = row_start[n], s1 = row_start[n + 1];
    float4 A = make_float4(0.f, 0.f, 0.f, 0.f);
    float4 B = make_float4(0.f, 0.f, 0.f, 0.f);
    float4 C = make_float4(0.f, 0.f, 0.f, 0.f);
    float4 D = make_float4(0.f, 0.f, 0.f, 0.f);
    for (int j0 = s0; j0 < s1; j0 += 16) {
        int idx = j0 + l16;
        int sl = (idx < s1) ? csr[idx] : 0;
        int cnt = s1 - j0; if (cnt > 16) cnt = 16;
        int j = 0;
        if (j + 16 <= cnt) {
            int eA = __shfl(sl, base + j + q, 64);
            int eB = __shfl(sl, base + j + 4 + q, 64);
            int eC = __shfl(sl, base + j + 8 + q, 64);
            int eD = __shfl(sl, base + j + 12 + q, 64);
            float4 vA = *(const float4*)&h2[eA * FC + c * 4];
            float4 vB = *(const float4*)&h2[eB * FC + c * 4];
            float4 vC = *(const float4*)&h2[eC * FC + c * 4];
            float4 vD = *(const float4*)&h2[eD * FC + c * 4];
            A = add4(A, vA); B = add4(B, vB);
            C = add4(C, vC); D = add4(D, vD);
            j += 16;
        }
        if (j + 8 <= cnt) {
            int eA = __shfl(sl, base + j + q, 64);
            int eB = __shfl(sl, base + j + 4 + q, 64);
            float4 vA = *(const float4*)&h2[eA * FC + c * 4];
            float4 vB = *(const float4*)&h2[eB * FC + c * 4];
            A = add4(A, vA); B = add4(B, vB);
            j += 8;
        }
        if (j + 4 <= cnt) {
            int eA = __shfl(sl, base + j + q, 64);
            float4 vA = *(const float4*)&h2[eA * FC + c * 4];
            A = add4(A, vA);
            j += 4;
        }
        int rem = cnt - j;
        if (rem > 0) {
            int jj = base + j + (q < rem ? q : 0);
            int eA = __shfl(sl, jj, 64);
            float wA = (q < rem) ? 1.f : 0.f;
            float4 vA = *(const float4*)&h2[eA * FC + c * 4];
            A = fma4(vA, wA, A);
        }
    }
    float4 r = add4(add4(A, B), add4(C, D));
    r = xor_add4(r, 4);
    r = xor_add4(r, 8);                     // reduce across q within subgroup
    if (q == 0) {
        float dn = dinv[n];
        float4 self = *(const float4*)&h2[n * FC + c * 4];    // h2' already scaled
        float4 bq = *(const float4*)&b2[c * 4];
        float4 p;
        p.x = fmaf(r.x + self.x, dn, bq.x);
        p.y = fmaf(r.y + self.y, dn, bq.y);
        p.z = fmaf(r.z + self.z, dn, bq.z);
        p.w = fmaf(r.w + self.w, dn, bq.w);
        *(float4*)&out[n * FC + c * 4] = p;
    }
}

extern "C" void kernel_launch(void* const* d_in, const int* in_sizes, int n_in,
                              void* d_out, int out_size, void* d_ws, size_t ws_size,
                              hipStream_t stream) {
    const float* x  = (const float*)d_in[0];
    const int*   ei = (const int*)d_in[1];
    const float* W1 = (const float*)d_in[2];
    const float* b1 = (const float*)d_in[3];
    const float* W2 = (const float*)d_in[4];
    const float* b2 = (const float*)d_in[5];
    float* out = (float*)d_out;

    char* ws = (char*)d_ws;
    int*   deg       = (int*)(ws + 0);                       // 400 KB
    int*   row_start = (int*)(ws + 512 * 1024);              // 400 KB + 4
    float* dinv      = (float*)(ws + 1024 * 1024);           // 400 KB
    int*   flag      = (int*)(ws + 1536 * 1024);             // 4 B
    int*   partial   = (int*)(ws + 1540 * 1024);             // 392 B
    int*   csr       = (int*)(ws + 2ull * 1024 * 1024);      // 6.4 MB  [fill..agg2]
    float* h1        = (float*)(ws + 9ull * 1024 * 1024);    // 25.6 MB [fused..agg1g]
    v2i*   packed    = (v2i*)(ws + 35ull * 1024 * 1024);     // 12.8 MB [fused..fill]
    float* h2        = (float*)(ws + 35ull * 1024 * 1024);   // 6.4 MB  [agg1g..agg2]
                                                             //   aliases packed (dead)

    detect_k<<<1, 64, 0, stream>>>(ei, flag);
    (void)hipMemsetAsync(deg, 0, NN * sizeof(int), stream);
    fused_k<<<NB_FUSED, 256, 0, stream>>>(ei, flag, deg, packed, x, W1, h1);
    scan_sum_k<<<NB_SCAN, 256, 0, stream>>>(deg, partial, dinv);
    scale1_k<<<(NN * 16 + 255) / 256, 256, 0, stream>>>(h1, dinv);
    scan_part_k<<<1, 128, 0, stream>>>(partial);
    scan_out_k<<<NB_SCAN, 256, 0, stream>>>(deg, partial, row_start);
    fill_k<<<(NE + 255) / 256, 256, 0, stream>>>(packed, row_start, csr);

    agg1g_k<<<(NN + 3) / 4, 256, 0, stream>>>(csr, row_start, h1, dinv, b1, W2, h2);
    agg2_k<<<(NN + 15) / 16, 256, 0, stream>>>(csr, row_start, h2, dinv, b2, out);
}